// Round 9
// baseline (420.556 us; speedup 1.0000x reference)
//
#include <hip/hip_runtime.h>
#include <cstddef>

#define NN 8192
#define CC 128

typedef unsigned short u16;
typedef _Float16 half_t;
typedef _Float16 v4h __attribute__((ext_vector_type(4)));
typedef float v4f __attribute__((ext_vector_type(4)));

// ---- LDS address (AS3 offset) ----
typedef __attribute__((address_space(3))) void lvoid_t;
static __device__ inline unsigned lds_addr(void* p) {
  return (unsigned)(unsigned long long)(lvoid_t*)p;
}

// ---------------- CSR build ----------------

__global__ __launch_bounds__(256) void count_deg_int_k(const int* __restrict__ dst, int* degi, int E) {
  int i = blockIdx.x * 256 + threadIdx.x;
  if (i < E) atomicAdd(&degi[dst[i]], 1);
}

__global__ __launch_bounds__(256) void scan_k(const int* __restrict__ degi, int* __restrict__ rowstart,
                                              int* __restrict__ cursor, float* __restrict__ dinv) {
  __shared__ int partial[256];
  int t = threadIdx.x;
  int base = t * 32;
  int local[32];
  int s = 0;
#pragma unroll
  for (int i = 0; i < 32; ++i) {
    int d = degi[base + i];
    dinv[base + i] = rsqrtf((float)(d + 1));
    local[i] = s; s += d;
  }
  partial[t] = s;
  __syncthreads();
  for (int off = 1; off < 256; off <<= 1) {
    int v = (t >= off) ? partial[t - off] : 0;
    __syncthreads();
    partial[t] += v;
    __syncthreads();
  }
  int offset = partial[t] - s;
#pragma unroll
  for (int i = 0; i < 32; ++i) {
    rowstart[base + i] = offset + local[i];
    cursor[base + i] = offset + local[i];
  }
  if (t == 255) rowstart[NN] = offset + s;
}

__global__ __launch_bounds__(256) void bucket_k(const int* __restrict__ src, const int* __restrict__ dst,
    int* __restrict__ cursor, int* __restrict__ col, int E) {
  int e = blockIdx.x * 256 + threadIdx.x;
  if (e >= E) return;
  int d = dst[e];
  int pos = atomicAdd(&cursor[d], 1);
  col[pos] = src[e];
}

// h1 = dd*(sum_in xws[s] + xws[d]) + conv_b + x   where xws = (x@W)*dinv[row]
__global__ __launch_bounds__(256) void gather_k(const int* __restrict__ rowstart, const int* __restrict__ col,
    const float* __restrict__ xws, const float* __restrict__ dinv, const float* __restrict__ cb,
    const float* __restrict__ x, float* __restrict__ h1) {
  int d = blockIdx.x * 2 + (threadIdx.x >> 7);
  int c = threadIdx.x & 127;
  int j0 = rowstart[d], j1 = rowstart[d + 1];
  float dd = dinv[d];
  float sum = 0.f;
  float v = 0.f;
  if (j0 < j1) v = xws[(size_t)col[j0] * CC + c];
  for (int j = j0; j < j1; ++j) {
    float v_next = 0.f;
    if (j + 1 < j1) v_next = xws[(size_t)col[j + 1] * CC + c];
    sum += v;
    v = v_next;
  }
  int idx = d * CC + c;
  sum += xws[idx];
  h1[idx] = sum * dd + cb[c] + x[idx];
}

// ---------------- BN helpers ----------------

__global__ __launch_bounds__(256) void bn_stats_k(const float* __restrict__ X,
    float* __restrict__ sums, float* __restrict__ sumsq) {
  int t = threadIdx.x;
  int c = t & 127, rg = t >> 7;
  int r0 = blockIdx.x * 64;
  float s = 0.f, sq = 0.f;
  for (int i = 0; i < 32; ++i) {
    float v = X[(size_t)(r0 + rg + 2 * i) * CC + c];
    s += v; sq += v * v;
  }
  atomicAdd(&sums[c], s);
  atomicAdd(&sumsq[c], sq);
}

__global__ __launch_bounds__(256) void combine_k(const float* __restrict__ h1, const float* __restrict__ h2,
    const float* __restrict__ st, const float* __restrict__ g1, const float* __restrict__ be1,
    const float* __restrict__ g2, const float* __restrict__ be2, float* __restrict__ out) {
  int idx = blockIdx.x * 256 + threadIdx.x;
  int c = idx & 127;
  float mu1 = st[c] * (1.f / NN);
  float var1 = st[128 + c] * (1.f / NN) - mu1 * mu1;
  float sc1 = g1[c] * rsqrtf(var1 + 1e-5f);
  float sh1 = be1[c] - mu1 * sc1;
  float mu2 = st[256 + c] * (1.f / NN);
  float var2 = st[384 + c] * (1.f / NN) - mu2 * mu2;
  float sc2 = g2[c] * rsqrtf(var2 + 1e-5f);
  float sh2 = be2[c] - mu2 * sc2;
  out[idx] = sc1 * h1[idx] + sh1 + sc2 * h2[idx] + sh2;
}

__global__ __launch_bounds__(256) void bn_apply_k(const float* __restrict__ h, const float* __restrict__ st,
    const float* __restrict__ g3, const float* __restrict__ be3, float* __restrict__ out) {
  int idx = blockIdx.x * 256 + threadIdx.x;
  int c = idx & 127;
  float mu = st[512 + c] * (1.f / NN);
  float var = st[640 + c] * (1.f / NN) - mu * mu;
  float sc = g3[c] * rsqrtf(var + 1e-5f);
  float sh = be3[c] - mu * sc;
  out[idx] = sc * h[idx] + sh;
}

// ---------------- MFMA GEMM v2 (fp16 inputs, fp32 accumulate/epilogue) — unchanged ----------------
template <int KT>
__global__ __launch_bounds__(256, 2) void mgemm_k(const float* __restrict__ A, const float* __restrict__ W,
    const float* __restrict__ bias, const float* __restrict__ resid, const float* __restrict__ dscale,
    float* __restrict__ out, int N, float scale, int relu, int ofp16) {
  constexpr int NCH = KT / 16;
  __shared__ u16 WL[NCH][2048];   // per chunk: [16 k][128 n] fp16 in tr-read subtile layout
  const int t = threadIdx.x;
  const int wv = t >> 6, l = t & 63;
  const int row0 = blockIdx.x * 16;
  const int n0 = blockIdx.y * 128;
  const int lq = l & 15, lg = l >> 4;

  // ---- stage W chunks (each wave stages chunks wv, wv+4, ...) ----
  const int s_hdb = l >> 5;
  const int s_kg = (l >> 3) & 3;
  const int s_km = (l >> 1) & 3;
  const int s_dm0 = (l & 1) * 8;
  for (int ch = wv; ch < NCH; ch += 4) {
    int krow = ch * 16 + s_kg * 4 + s_km;
    const float* wr = W + (size_t)krow * N + n0;
#pragma unroll
    for (int i = 0; i < 4; ++i) {
      const float* src = wr + (i * 2 + s_hdb) * 16 + s_dm0;
      float4 f0 = *(const float4*)src;
      float4 f1 = *(const float4*)(src + 4);
      unsigned u0 = __builtin_bit_cast(unsigned, __builtin_amdgcn_cvt_pkrtz(f0.x, f0.y));
      unsigned u1 = __builtin_bit_cast(unsigned, __builtin_amdgcn_cvt_pkrtz(f0.z, f0.w));
      unsigned u2 = __builtin_bit_cast(unsigned, __builtin_amdgcn_cvt_pkrtz(f1.x, f1.y));
      unsigned u3 = __builtin_bit_cast(unsigned, __builtin_amdgcn_cvt_pkrtz(f1.z, f1.w));
      *(uint4*)&WL[ch][i * 512 + l * 8] = make_uint4(u0, u1, u2, u3);
    }
  }

  // ---- A fragments (fp32 direct from global): A[row0+lq][i*16 + lg*4 .. +3] ----
  v4f af[NCH];
#pragma unroll
  for (int i = 0; i < NCH; ++i)
    af[i] = *(const v4f*)(A + (size_t)(row0 + lq) * KT + i * 16 + lg * 4);

  __syncthreads();

  v4f acc[2];
  acc[0] = (v4f){0.f, 0.f, 0.f, 0.f};
  acc[1] = (v4f){0.f, 0.f, 0.f, 0.f};
  // tr-read base: chunk stride 4096B; hd = wv*2+c -> wv*1024 + c*512 byte offset
  const unsigned va0 = lds_addr(&WL[0][0]) + (unsigned)(wv * 1024 + l * 8);

  unsigned long long cur0, cur1, nxt0, nxt1;
  asm volatile("ds_read_b64_tr_b16 %0, %2 offset:0\n\t"
               "ds_read_b64_tr_b16 %1, %2 offset:512"
               : "=v"(cur0), "=v"(cur1) : "v"(va0));
#pragma unroll
  for (int i = 0; i < NCH; ++i) {
    if (i + 1 < NCH) {
      unsigned va = va0 + (unsigned)((i + 1) * 4096);
      asm volatile("ds_read_b64_tr_b16 %0, %2 offset:0\n\t"
                   "ds_read_b64_tr_b16 %1, %2 offset:512"
                   : "=v"(nxt0), "=v"(nxt1) : "v"(va));
      asm volatile("s_waitcnt lgkmcnt(2)" ::: "memory");
    } else {
      asm volatile("s_waitcnt lgkmcnt(0)" ::: "memory");
    }
    __builtin_amdgcn_sched_barrier(0);
    v4h a;
    a[0] = (half_t)af[i][0]; a[1] = (half_t)af[i][1];
    a[2] = (half_t)af[i][2]; a[3] = (half_t)af[i][3];
    acc[0] = __builtin_amdgcn_mfma_f32_16x16x16f16(a, __builtin_bit_cast(v4h, cur0), acc[0], 0, 0, 0);
    acc[1] = __builtin_amdgcn_mfma_f32_16x16x16f16(a, __builtin_bit_cast(v4h, cur1), acc[1], 0, 0, 0);
    cur0 = nxt0; cur1 = nxt1;
  }

  // ---- epilogue: D[row0 + lg*4+reg][n0 + hd*16 + lq] ----
#pragma unroll
  for (int c = 0; c < 2; ++c) {
    int hd = wv * 2 + c;
    float bcv = bias ? bias[n0 + hd * 16 + lq] : 0.f;
#pragma unroll
    for (int reg = 0; reg < 4; ++reg) {
      int row = row0 + lg * 4 + reg;
      float ds = dscale ? dscale[row] : 1.f;
      float r = (acc[c][reg] + bcv) * scale * ds;
      if (relu) r = fmaxf(r, 0.f);
      size_t o = (size_t)row * N + n0 + hd * 16 + lq;
      if (ofp16) {
        ((half_t*)out)[o] = (half_t)r;
      } else {
        if (resid) r += resid[o];
        out[o] = r;
      }
    }
  }
}

// ---------------- flash attention v10: 8 waves/block (4 waves/SIMD), in-block merge ----------------
// Block = 512 threads = 8 waves; block owns 16 q-rows x ALL 512 keys; wave wv owns keys
// [wv*64, wv*64+64) as 4 chunks of 16. Grid 512 -> 2 blocks/CU x 8 waves = 16 waves/CU
// = 4 waves/SIMD (2x v9, whose occupancy=19.8% was the binding constraint: hbm 2.0 TB/s,
// VALUBusy 8%, nothing saturated). Per-chunk structure byte-identical to the verified v8.
// LDS: 8 x 2 x 4KB staging (64KB; f32 merge regions alias it) + 4KB L-sums = 68KB
// -> exactly 2 blocks/CU. Merge: 8-way tree sum, thread t sums q=t>>5, d group (t&31)*4.
__global__ __launch_bounds__(512, 4) void attn_k(const half_t* __restrict__ Qh,
    const half_t* __restrict__ Kh, const half_t* __restrict__ Vh, const float* __restrict__ bias,
    float* __restrict__ out) {
  __shared__ u16 VL[8][2][2048];   // 64 KB V staging; epilogue alias: f32 FB[wv][q][128]
  __shared__ float LB[8][8][16];   // per-wave l sums [wv][hd][q]
  const int t = threadIdx.x;
  const int wv = t >> 6;
  const int l = t & 63;
  const int qtg = blockIdx.x;      // q-tile 0..511 (16 rows)
  const int b = qtg >> 5;
  const int node_t = qtg * 16;
  const int key0 = wv * 64;
  const int kb0 = b * 512 + key0;
  const int lq = l & 15;
  const int lg = l >> 4;

  // Q fragments (B-layout): lane holds Q[node_t+lq][hd*16 + lg*4 .. +3]
  v4h qf[8];
#pragma unroll
  for (int hd = 0; hd < 8; ++hd)
    qf[hd] = *(const v4h*)(Qh + (size_t)(node_t + lq) * CC + hd * 16 + lg * 4);

  v4f oacc[8];
  float lacc[8];
#pragma unroll
  for (int hd = 0; hd < 8; ++hd) { oacc[hd] = (v4f){0.f, 0.f, 0.f, 0.f}; lacc[hd] = 0.f; }

  // V staging decode (lane-fixed): instr i, lane l -> LDS ushort o = i*512 + l*8
  const int v_hdb = l >> 5;
  const int v_kg = (l >> 3) & 3;
  const int v_km = (l >> 1) & 3;
  const int v_dm0 = (l & 1) * 8;
  uint4 vreg[4];

  auto vload = [&](int ch) {
#pragma unroll
    for (int i = 0; i < 4; ++i)
      vreg[i] = *(const uint4*)(Vh + (size_t)(kb0 + ch * 16 + v_kg * 4 + v_km) * CC
                                + (i * 2 + v_hdb) * 16 + v_dm0);
  };
  auto vwrite = [&](int bf) {
#pragma unroll
    for (int i = 0; i < 4; ++i)
      *(uint4*)&VL[wv][bf][i * 512 + l * 8] = vreg[i];
  };

  const unsigned lbase = lds_addr(&VL[wv][0][0]);
  const float* bb = bias + ((size_t)node_t * 512 + key0) * 8 + (size_t)lq * 4096;

  // prologue: stage chunk 0
  vload(0);
  vwrite(0);

  for (int ch = 0; ch < 4; ++ch) {
    const int bf = ch & 1;
    if (ch < 3) vload(ch + 1);

    // K fragments (A-layout): lane holds K[kb0+ch*16+lq][hd*16 + lg*4 .. +3]
    v4h kf[8];
#pragma unroll
    for (int hd = 0; hd < 8; ++hd)
      kf[hd] = *(const v4h*)(Kh + (size_t)(kb0 + ch * 16 + lq) * CC + hd * 16 + lg * 4);

    // drain prior ds_writes, then HW-transpose-read V fragments for this chunk
    asm volatile("s_waitcnt lgkmcnt(0)" ::: "memory");
    __builtin_amdgcn_sched_barrier(0);
    unsigned va = lbase + (unsigned)(bf * 4096) + (unsigned)(l * 8);
    unsigned long long vfr[8];
#pragma unroll
    for (int hd = 0; hd < 8; ++hd)
      asm volatile("ds_read_b64_tr_b16 %0, %1 offset:%2"
                   : "=v"(vfr[hd]) : "v"(va), "i"(hd * 512));
    asm volatile("s_waitcnt lgkmcnt(0)" ::: "memory");
    __builtin_amdgcn_sched_barrier(0);

    if (ch < 3) vwrite(bf ^ 1);   // stage next chunk into other buffer (verified position)

    const v4f z = (v4f){0.f, 0.f, 0.f, 0.f};
#pragma unroll
    for (int hg = 0; hg < 2; ++hg) {
      // bias float4 per (reg): bias[node_t+lq][key0+ch*16+lg*4+reg][hg*4 .. +3]
      v4f bfr[4];
#pragma unroll
      for (int reg = 0; reg < 4; ++reg)
        bfr[reg] = *(const v4f*)(bb + (size_t)(ch * 16 + lg * 4 + reg) * 8 + hg * 4);

      v4f stv[4];
#pragma unroll
      for (int j = 0; j < 4; ++j)
        stv[j] = __builtin_amdgcn_mfma_f32_16x16x16f16(kf[hg * 4 + j], qf[hg * 4 + j], z, 0, 0, 0);

#pragma unroll
      for (int j = 0; j < 4; ++j) {
        const int hd = hg * 4 + j;
        float pr0 = __expf(stv[j][0] + bfr[0][j] - 4.f);
        float pr1 = __expf(stv[j][1] + bfr[1][j] - 4.f);
        float pr2 = __expf(stv[j][2] + bfr[2][j] - 4.f);
        float pr3 = __expf(stv[j][3] + bfr[3][j] - 4.f);
        lacc[hd] += pr0 + pr1 + pr2 + pr3;
        unsigned u0 = __builtin_bit_cast(unsigned, __builtin_amdgcn_cvt_pkrtz(pr0, pr1));
        unsigned u1 = __builtin_bit_cast(unsigned, __builtin_amdgcn_cvt_pkrtz(pr2, pr3));
        uint2 pu = make_uint2(u0, u1);
        v4h pa = __builtin_bit_cast(v4h, pu);
        v4h vf = __builtin_bit_cast(v4h, vfr[hd]);
        oacc[hd] = __builtin_amdgcn_mfma_f32_16x16x16f16(pa, vf, oacc[hd], 0, 0, 0);
      }
    }
  }

  // ---- in-block merge across the 8 key-range waves ----
#pragma unroll
  for (int hd = 0; hd < 8; ++hd) {
    float v = lacc[hd];
    v += __shfl_xor(v, 16);
    v += __shfl_xor(v, 32);
    lacc[hd] = v;
  }
  if (l < 16) {
#pragma unroll
    for (int hd = 0; hd < 8; ++hd)
      LB[wv][hd][l] = lacc[hd];
  }

  // dump oacc into own 8KB region (aliases own V staging — loop is done with it)
  float* FB = (float*)VL;   // [wv][q(16)][d(128)] f32, wv stride 2048 floats = 8KB
#pragma unroll
  for (int hd = 0; hd < 8; ++hd)
#pragma unroll
    for (int reg = 0; reg < 4; ++reg)
      FB[wv * 2048 + (lg * 4 + reg) * 128 + hd * 16 + lq] = oacc[hd][reg];

  __syncthreads();

  // final: thread t -> q = t>>5, d0 = (t&31)*4; sum 8 waves, divide by L, write f32
  const int q = t >> 5, d0 = (t & 31) * 4;
  const int hd = d0 >> 4;   // 4-float group never crosses a head boundary
  float L = 0.f;
#pragma unroll
  for (int r = 0; r < 8; ++r) L += LB[r][hd][q];
  float inv = 1.f / L;
  float res[4];
#pragma unroll
  for (int j = 0; j < 4; ++j) {
    int d = d0 + j;
    float v = 0.f;
#pragma unroll
    for (int r = 0; r < 8; ++r) v += FB[r * 2048 + q * 128 + d];
    res[j] = v * inv;
  }
  float* po = out + (size_t)(node_t + q) * CC + d0;
  *(float4*)po = make_float4(res[0], res[1], res[2], res[3]);
}

// ---------------- launcher ----------------

extern "C" void kernel_launch(void* const* d_in, const int* in_sizes, int n_in,
                              void* d_out, int out_size, void* d_ws, size_t ws_size,
                              hipStream_t stream) {
  const float* x      = (const float*)d_in[0];
  const int*   ei     = (const int*)d_in[1];
  const float* bias   = (const float*)d_in[3];
  const float* conv_w = (const float*)d_in[4];
  const float* conv_b = (const float*)d_in[5];
  const float* wq = (const float*)d_in[6];
  const float* bq = (const float*)d_in[7];
  const float* wk = (const float*)d_in[8];
  const float* bk = (const float*)d_in[9];
  const float* wv = (const float*)d_in[10];
  const float* bv = (const float*)d_in[11];
  const float* wo = (const float*)d_in[12];
  const float* bo = (const float*)d_in[13];
  const float* w1 = (const float*)d_in[14];
  const float* b1 = (const float*)d_in[15];
  const float* w2 = (const float*)d_in[16];
  const float* b2 = (const float*)d_in[17];
  const float* g1 = (const float*)d_in[18];
  const float* be1 = (const float*)d_in[19];
  const float* g2 = (const float*)d_in[20];
  const float* be2 = (const float*)d_in[21];
  const float* g3 = (const float*)d_in[22];
  const float* be3 = (const float*)d_in[23];
  int E = in_sizes[1] / 2;

  float* ws = (float*)d_ws;
  const size_t NC = (size_t)NN * CC;
  float* xw     = ws;            // conv xws
  float* h1pre  = ws + NC;
  float* qb     = ws + 2 * NC;   // fp16 Q (2MB used)
  float* kb     = ws + 3 * NC;   // fp16 K
  float* vb     = ws + 4 * NC;   // fp16 V
  float* h2pre  = ws + 5 * NC;   // wo-gemm out
  float* outbuf = ws + 6 * NC;   // attn f32 out; then combine out (MLP input)
  float* hid    = ws + 2 * NC;   // reuse qb+kb after attention
  float* h3pre  = ws + 4 * NC;   // reuse vb after attention consumed
  float* st     = ws + 7 * NC;   // 768 floats BN sums
  float* dinv   = ws + 7 * NC + 768;
  int*   degi     = (int*)(ws + 7 * NC + 768 + NN);
  int*   rowstart = degi + NN;
  int*   cursor   = rowstart + NN + 1;
  int*   col      = cursor + NN;

  hipMemsetAsync(degi, 0, NN * sizeof(int), stream);
  hipMemsetAsync(st, 0, 768 * sizeof(float), stream);

  // ---- GCN branch
  count_deg_int_k<<<(E + 255) / 256, 256, 0, stream>>>(ei + E, degi, E);
  scan_k<<<1, 256, 0, stream>>>(degi, rowstart, cursor, dinv);
  bucket_k<<<(E + 255) / 256, 256, 0, stream>>>(ei, ei + E, cursor, col, E);
  mgemm_k<128><<<dim3(NN / 16, 1), 256, 0, stream>>>(x, conv_w, nullptr, nullptr, dinv, xw, CC, 1.f, 0, 0);
  gather_k<<<NN / 2, 256, 0, stream>>>(rowstart, col, xw, dinv, conv_b, x, h1pre);
  bn_stats_k<<<NN / 64, 256, 0, stream>>>(h1pre, st + 0, st + 128);

  // ---- attention branch (Q/K/V as fp16; attn writes merged f32 directly)
  mgemm_k<128><<<dim3(NN / 16, 1), 256, 0, stream>>>(x, wq, bq, nullptr, nullptr, qb, CC, 0.25f, 0, 1);
  mgemm_k<128><<<dim3(NN / 16, 1), 256, 0, stream>>>(x, wk, bk, nullptr, nullptr, kb, CC, 1.f, 0, 1);
  mgemm_k<128><<<dim3(NN / 16, 1), 256, 0, stream>>>(x, wv, bv, nullptr, nullptr, vb, CC, 1.f, 0, 1);
  attn_k<<<512, 512, 0, stream>>>((const half_t*)qb, (const half_t*)kb, (const half_t*)vb, bias, outbuf);
  mgemm_k<128><<<dim3(NN / 16, 1), 256, 0, stream>>>(outbuf, wo, bo, x, nullptr, h2pre, CC, 1.f, 0, 0);
  bn_stats_k<<<NN / 64, 256, 0, stream>>>(h2pre, st + 256, st + 384);

  // ---- combine + MLP (BN finalizes fused)
  combine_k<<<NC / 256, 256, 0, stream>>>(h1pre, h2pre, st, g1, be1, g2, be2, outbuf);
  mgemm_k<128><<<dim3(NN / 16, 2), 256, 0, stream>>>(outbuf, w1, b1, nullptr, nullptr, hid, 2 * CC, 1.f, 1, 0);
  mgemm_k<256><<<dim3(NN / 16, 1), 256, 0, stream>>>(hid, w2, b2, outbuf, nullptr, h3pre, CC, 1.f, 0, 0);
  bn_stats_k<<<NN / 64, 256, 0, stream>>>(h3pre, st + 512, st + 640);
  bn_apply_k<<<NC / 256, 256, 0, stream>>>(h3pre, st, g3, be3, (float*)d_out);
}

// Round 12
// 405.094 us; speedup vs baseline: 1.0382x; 1.0382x over previous
//
#include <hip/hip_runtime.h>
#include <cstddef>

#define NN 8192
#define CC 128

typedef unsigned short u16;
typedef _Float16 half_t;
typedef _Float16 v4h __attribute__((ext_vector_type(4)));
typedef float v4f __attribute__((ext_vector_type(4)));

// ---- LDS address (AS3 offset) ----
typedef __attribute__((address_space(3))) void lvoid_t;
static __device__ inline unsigned lds_addr(void* p) {
  return (unsigned)(unsigned long long)(lvoid_t*)p;
}

// ---------------- CSR build ----------------

__global__ __launch_bounds__(256) void count_deg_int_k(const int* __restrict__ dst, int* degi, int E) {
  int i = blockIdx.x * 256 + threadIdx.x;
  if (i < E) atomicAdd(&degi[dst[i]], 1);
}

__global__ __launch_bounds__(256) void scan_k(const int* __restrict__ degi, int* __restrict__ rowstart,
                                              int* __restrict__ cursor, float* __restrict__ dinv) {
  __shared__ int partial[256];
  int t = threadIdx.x;
  int base = t * 32;
  int local[32];
  int s = 0;
#pragma unroll
  for (int i = 0; i < 32; ++i) {
    int d = degi[base + i];
    dinv[base + i] = rsqrtf((float)(d + 1));
    local[i] = s; s += d;
  }
  partial[t] = s;
  __syncthreads();
  for (int off = 1; off < 256; off <<= 1) {
    int v = (t >= off) ? partial[t - off] : 0;
    __syncthreads();
    partial[t] += v;
    __syncthreads();
  }
  int offset = partial[t] - s;
#pragma unroll
  for (int i = 0; i < 32; ++i) {
    rowstart[base + i] = offset + local[i];
    cursor[base + i] = offset + local[i];
  }
  if (t == 255) rowstart[NN] = offset + s;
}

__global__ __launch_bounds__(256) void bucket_k(const int* __restrict__ src, const int* __restrict__ dst,
    int* __restrict__ cursor, int* __restrict__ col, int E) {
  int e = blockIdx.x * 256 + threadIdx.x;
  if (e >= E) return;
  int d = dst[e];
  int pos = atomicAdd(&cursor[d], 1);
  col[pos] = src[e];
}

// h1 = dd*(sum_in xws[s] + xws[d]) + conv_b + x   where xws = (x@W)*dinv[row]
__global__ __launch_bounds__(256) void gather_k(const int* __restrict__ rowstart, const int* __restrict__ col,
    const float* __restrict__ xws, const float* __restrict__ dinv, const float* __restrict__ cb,
    const float* __restrict__ x, float* __restrict__ h1) {
  int d = blockIdx.x * 2 + (threadIdx.x >> 7);
  int c = threadIdx.x & 127;
  int j0 = rowstart[d], j1 = rowstart[d + 1];
  float dd = dinv[d];
  float sum = 0.f;
  float v = 0.f;
  if (j0 < j1) v = xws[(size_t)col[j0] * CC + c];
  for (int j = j0; j < j1; ++j) {
    float v_next = 0.f;
    if (j + 1 < j1) v_next = xws[(size_t)col[j + 1] * CC + c];
    sum += v;
    v = v_next;
  }
  int idx = d * CC + c;
  sum += xws[idx];
  h1[idx] = sum * dd + cb[c] + x[idx];
}

// ---------------- BN helpers ----------------

__global__ __launch_bounds__(256) void bn_stats_k(const float* __restrict__ X,
    float* __restrict__ sums, float* __restrict__ sumsq) {
  int t = threadIdx.x;
  int c = t & 127, rg = t >> 7;
  int r0 = blockIdx.x * 64;
  float s = 0.f, sq = 0.f;
  for (int i = 0; i < 32; ++i) {
    float v = X[(size_t)(r0 + rg + 2 * i) * CC + c];
    s += v; sq += v * v;
  }
  atomicAdd(&sums[c], s);
  atomicAdd(&sumsq[c], sq);
}

__global__ __launch_bounds__(256) void combine_k(const float* __restrict__ h1, const float* __restrict__ h2,
    const float* __restrict__ st, const float* __restrict__ g1, const float* __restrict__ be1,
    const float* __restrict__ g2, const float* __restrict__ be2, float* __restrict__ out) {
  int idx = blockIdx.x * 256 + threadIdx.x;
  int c = idx & 127;
  float mu1 = st[c] * (1.f / NN);
  float var1 = st[128 + c] * (1.f / NN) - mu1 * mu1;
  float sc1 = g1[c] * rsqrtf(var1 + 1e-5f);
  float sh1 = be1[c] - mu1 * sc1;
  float mu2 = st[256 + c] * (1.f / NN);
  float var2 = st[384 + c] * (1.f / NN) - mu2 * mu2;
  float sc2 = g2[c] * rsqrtf(var2 + 1e-5f);
  float sh2 = be2[c] - mu2 * sc2;
  out[idx] = sc1 * h1[idx] + sh1 + sc2 * h2[idx] + sh2;
}

__global__ __launch_bounds__(256) void bn_apply_k(const float* __restrict__ h, const float* __restrict__ st,
    const float* __restrict__ g3, const float* __restrict__ be3, float* __restrict__ out) {
  int idx = blockIdx.x * 256 + threadIdx.x;
  int c = idx & 127;
  float mu = st[512 + c] * (1.f / NN);
  float var = st[640 + c] * (1.f / NN) - mu * mu;
  float sc = g3[c] * rsqrtf(var + 1e-5f);
  float sh = be3[c] - mu * sc;
  out[idx] = sc * h[idx] + sh;
}

// ---------------- MFMA GEMM (fp16 inputs, fp32 accumulate/epilogue) ----------------
// Round-9 structure with one fix: ALL tr-reads address through the single base register va0
// (live across the whole k-loop, so the register allocator cannot alias any async ds_read
// output with it) using compile-time offset: immediates, plus "=&v" early-clobbers.
// Root cause being fixed: paired "=v" outputs with a per-iteration address temp allowed
// output/address register aliasing; ds_read writes its result ASYNCHRONOUSLY, so if the
// first read returned before the second issued, the second read used a corrupted address
// (intermittent; surfaced when v13's extra kernel perturbed register allocation).
template <int KT>
__global__ __launch_bounds__(256, 2) void mgemm_k(const float* __restrict__ A, const float* __restrict__ W,
    const float* __restrict__ bias, const float* __restrict__ resid, const float* __restrict__ dscale,
    float* __restrict__ out, int N, float scale, int relu, int ofp16) {
  constexpr int NCH = KT / 16;
  __shared__ u16 WL[NCH][2048];   // per chunk: [16 k][128 n] fp16 in tr-read subtile layout
  const int t = threadIdx.x;
  const int wv = t >> 6, l = t & 63;
  const int row0 = blockIdx.x * 16;
  const int n0 = blockIdx.y * 128;
  const int lq = l & 15, lg = l >> 4;

  // ---- stage W chunks (each wave stages chunks wv, wv+4, ...) ----
  const int s_hdb = l >> 5;
  const int s_kg = (l >> 3) & 3;
  const int s_km = (l >> 1) & 3;
  const int s_dm0 = (l & 1) * 8;
  for (int ch = wv; ch < NCH; ch += 4) {
    int krow = ch * 16 + s_kg * 4 + s_km;
    const float* wr = W + (size_t)krow * N + n0;
#pragma unroll
    for (int i = 0; i < 4; ++i) {
      const float* src = wr + (i * 2 + s_hdb) * 16 + s_dm0;
      float4 f0 = *(const float4*)src;
      float4 f1 = *(const float4*)(src + 4);
      unsigned u0 = __builtin_bit_cast(unsigned, __builtin_amdgcn_cvt_pkrtz(f0.x, f0.y));
      unsigned u1 = __builtin_bit_cast(unsigned, __builtin_amdgcn_cvt_pkrtz(f0.z, f0.w));
      unsigned u2 = __builtin_bit_cast(unsigned, __builtin_amdgcn_cvt_pkrtz(f1.x, f1.y));
      unsigned u3 = __builtin_bit_cast(unsigned, __builtin_amdgcn_cvt_pkrtz(f1.z, f1.w));
      *(uint4*)&WL[ch][i * 512 + l * 8] = make_uint4(u0, u1, u2, u3);
    }
  }

  // ---- A fragments (fp32 direct from global): A[row0+lq][i*16 + lg*4 .. +3] ----
  v4f af[NCH];
#pragma unroll
  for (int i = 0; i < NCH; ++i)
    af[i] = *(const v4f*)(A + (size_t)(row0 + lq) * KT + i * 16 + lg * 4);

  __syncthreads();

  v4f acc[2];
  acc[0] = (v4f){0.f, 0.f, 0.f, 0.f};
  acc[1] = (v4f){0.f, 0.f, 0.f, 0.f};
  // single base register for ALL tr-reads; chunk i at offset i*4096 (+512 for 2nd col-tile).
  // max offset = (NCH-1)*4096 + 512 < 65536 for KT<=256 -> fits 16-bit offset field.
  const unsigned va0 = lds_addr(&WL[0][0]) + (unsigned)(wv * 1024 + l * 8);

  unsigned long long cur0, cur1, nxt0, nxt1;
  asm volatile("ds_read_b64_tr_b16 %0, %2 offset:0\n\t"
               "ds_read_b64_tr_b16 %1, %2 offset:512"
               : "=&v"(cur0), "=&v"(cur1) : "v"(va0));
#pragma unroll
  for (int i = 0; i < NCH; ++i) {
    if (i + 1 < NCH) {
      asm volatile("ds_read_b64_tr_b16 %0, %2 offset:%3\n\t"
                   "ds_read_b64_tr_b16 %1, %2 offset:%4"
                   : "=&v"(nxt0), "=&v"(nxt1)
                   : "v"(va0), "i"((i + 1) * 4096), "i"((i + 1) * 4096 + 512));
      asm volatile("s_waitcnt lgkmcnt(2)" ::: "memory");
    } else {
      asm volatile("s_waitcnt lgkmcnt(0)" ::: "memory");
    }
    __builtin_amdgcn_sched_barrier(0);
    v4h a;
    a[0] = (half_t)af[i][0]; a[1] = (half_t)af[i][1];
    a[2] = (half_t)af[i][2]; a[3] = (half_t)af[i][3];
    acc[0] = __builtin_amdgcn_mfma_f32_16x16x16f16(a, __builtin_bit_cast(v4h, cur0), acc[0], 0, 0, 0);
    acc[1] = __builtin_amdgcn_mfma_f32_16x16x16f16(a, __builtin_bit_cast(v4h, cur1), acc[1], 0, 0, 0);
    cur0 = nxt0; cur1 = nxt1;
  }

  // ---- epilogue: D[row0 + lg*4+reg][n0 + hd*16 + lq] ----
#pragma unroll
  for (int c = 0; c < 2; ++c) {
    int hd = wv * 2 + c;
    float bcv = bias ? bias[n0 + hd * 16 + lq] : 0.f;
#pragma unroll
    for (int reg = 0; reg < 4; ++reg) {
      int row = row0 + lg * 4 + reg;
      float ds = dscale ? dscale[row] : 1.f;
      float r = (acc[c][reg] + bcv) * scale * ds;
      if (relu) r = fmaxf(r, 0.f);
      size_t o = (size_t)row * N + n0 + hd * 16 + lq;
      if (ofp16) {
        ((half_t*)out)[o] = (half_t)r;
      } else {
        if (resid) r += resid[o];
        out[o] = r;
      }
    }
  }
}

// ---------------- flash attention (v9-verified: 4 waves/block, in-block merge) ----------------
// (Byte-identical to the round-9 passing version. Its tr-read sequence is structurally immune
// to the aliasing hazard: va stays live across all 8 reads, so no output can share its reg.)
__global__ __launch_bounds__(256, 2) void attn_k(const half_t* __restrict__ Qh,
    const half_t* __restrict__ Kh, const half_t* __restrict__ Vh, const float* __restrict__ bias,
    float* __restrict__ out) {
  __shared__ u16 VL[4][2][2048];   // 32 KB V staging; epilogue alias: f32 FB[wv][q][128]
  __shared__ float LB[4][8][16];   // per-wave l sums [wv][hd][q]
  const int t = threadIdx.x;
  const int wv = t >> 6;
  const int l = t & 63;
  const int qtg = blockIdx.x;      // q-tile 0..511 (16 rows)
  const int b = qtg >> 5;
  const int node_t = qtg * 16;
  const int key0 = wv * 128;
  const int kb0 = b * 512 + key0;
  const int lq = l & 15;
  const int lg = l >> 4;

  // Q fragments (B-layout): lane holds Q[node_t+lq][hd*16 + lg*4 .. +3]
  v4h qf[8];
#pragma unroll
  for (int hd = 0; hd < 8; ++hd)
    qf[hd] = *(const v4h*)(Qh + (size_t)(node_t + lq) * CC + hd * 16 + lg * 4);

  v4f oacc[8];
  float lacc[8];
#pragma unroll
  for (int hd = 0; hd < 8; ++hd) { oacc[hd] = (v4f){0.f, 0.f, 0.f, 0.f}; lacc[hd] = 0.f; }

  // V staging decode (lane-fixed): instr i, lane l -> LDS ushort o = i*512 + l*8
  const int v_hdb = l >> 5;
  const int v_kg = (l >> 3) & 3;
  const int v_km = (l >> 1) & 3;
  const int v_dm0 = (l & 1) * 8;
  uint4 vreg[4];

  auto vload = [&](int ch) {
#pragma unroll
    for (int i = 0; i < 4; ++i)
      vreg[i] = *(const uint4*)(Vh + (size_t)(kb0 + ch * 16 + v_kg * 4 + v_km) * CC
                                + (i * 2 + v_hdb) * 16 + v_dm0);
  };
  auto vwrite = [&](int bf) {
#pragma unroll
    for (int i = 0; i < 4; ++i)
      *(uint4*)&VL[wv][bf][i * 512 + l * 8] = vreg[i];
  };

  const unsigned lbase = lds_addr(&VL[wv][0][0]);
  const float* bb = bias + ((size_t)node_t * 512 + key0) * 8 + (size_t)lq * 4096;

  // prologue: stage chunk 0
  vload(0);
  vwrite(0);

  for (int ch = 0; ch < 8; ++ch) {
    const int bf = ch & 1;
    if (ch < 7) vload(ch + 1);

    // K fragments (A-layout): lane holds K[kb0+ch*16+lq][hd*16 + lg*4 .. +3]
    v4h kf[8];
#pragma unroll
    for (int hd = 0; hd < 8; ++hd)
      kf[hd] = *(const v4h*)(Kh + (size_t)(kb0 + ch * 16 + lq) * CC + hd * 16 + lg * 4);

    // drain prior ds_writes, then HW-transpose-read V fragments for this chunk
    asm volatile("s_waitcnt lgkmcnt(0)" ::: "memory");
    __builtin_amdgcn_sched_barrier(0);
    unsigned va = lbase + (unsigned)(bf * 4096) + (unsigned)(l * 8);
    unsigned long long vfr[8];
#pragma unroll
    for (int hd = 0; hd < 8; ++hd)
      asm volatile("ds_read_b64_tr_b16 %0, %1 offset:%2"
                   : "=v"(vfr[hd]) : "v"(va), "i"(hd * 512));
    asm volatile("s_waitcnt lgkmcnt(0)" ::: "memory");
    __builtin_amdgcn_sched_barrier(0);

    if (ch < 7) vwrite(bf ^ 1);   // stage next chunk into other buffer (verified position)

    const v4f z = (v4f){0.f, 0.f, 0.f, 0.f};
#pragma unroll
    for (int hg = 0; hg < 2; ++hg) {
      // bias float4 per (reg): bias[node_t+lq][key0+ch*16+lg*4+reg][hg*4 .. +3]
      v4f bfr[4];
#pragma unroll
      for (int reg = 0; reg < 4; ++reg)
        bfr[reg] = *(const v4f*)(bb + (size_t)(ch * 16 + lg * 4 + reg) * 8 + hg * 4);

      v4f stv[4];
#pragma unroll
      for (int j = 0; j < 4; ++j)
        stv[j] = __builtin_amdgcn_mfma_f32_16x16x16f16(kf[hg * 4 + j], qf[hg * 4 + j], z, 0, 0, 0);

#pragma unroll
      for (int j = 0; j < 4; ++j) {
        const int hd = hg * 4 + j;
        float pr0 = __expf(stv[j][0] + bfr[0][j] - 4.f);
        float pr1 = __expf(stv[j][1] + bfr[1][j] - 4.f);
        float pr2 = __expf(stv[j][2] + bfr[2][j] - 4.f);
        float pr3 = __expf(stv[j][3] + bfr[3][j] - 4.f);
        lacc[hd] += pr0 + pr1 + pr2 + pr3;
        unsigned u0 = __builtin_bit_cast(unsigned, __builtin_amdgcn_cvt_pkrtz(pr0, pr1));
        unsigned u1 = __builtin_bit_cast(unsigned, __builtin_amdgcn_cvt_pkrtz(pr2, pr3));
        uint2 pu = make_uint2(u0, u1);
        v4h pa = __builtin_bit_cast(v4h, pu);
        v4h vf = __builtin_bit_cast(v4h, vfr[hd]);
        oacc[hd] = __builtin_amdgcn_mfma_f32_16x16x16f16(pa, vf, oacc[hd], 0, 0, 0);
      }
    }
  }

  // ---- in-block merge across the 4 key-range waves ----
#pragma unroll
  for (int hd = 0; hd < 8; ++hd) {
    float v = lacc[hd];
    v += __shfl_xor(v, 16);
    v += __shfl_xor(v, 32);
    lacc[hd] = v;
  }
  if (l < 16) {
#pragma unroll
    for (int hd = 0; hd < 8; ++hd)
      LB[wv][hd][l] = lacc[hd];
  }

  // dump oacc into own 8KB region (aliases own V staging — loop is done with it)
  float* FB = (float*)VL;   // [wv][q(16)][d(128)] f32, wv stride 2048 floats = 8KB
#pragma unroll
  for (int hd = 0; hd < 8; ++hd)
#pragma unroll
    for (int reg = 0; reg < 4; ++reg)
      FB[wv * 2048 + (lg * 4 + reg) * 128 + hd * 16 + lq] = oacc[hd][reg];

  __syncthreads();

  // final: thread t -> q = t>>4, d0 = (t&15)*8; sum 4 waves, divide by L, write f32
  const int q = t >> 4, d0 = (t & 15) * 8;
  float res[8];
#pragma unroll
  for (int j = 0; j < 8; ++j) {
    int d = d0 + j, hd = d >> 4;
    float v = FB[q * 128 + d] + FB[2048 + q * 128 + d]
            + FB[4096 + q * 128 + d] + FB[6144 + q * 128 + d];
    float L = LB[0][hd][q] + LB[1][hd][q] + LB[2][hd][q] + LB[3][hd][q];
    res[j] = v / L;
  }
  float* po = out + (size_t)(node_t + q) * CC + d0;
  *(float4*)po       = make_float4(res[0], res[1], res[2], res[3]);
  *(float4*)(po + 4) = make_float4(res[4], res[5], res[6], res[7]);
}

// ---------------- launcher ----------------

extern "C" void kernel_launch(void* const* d_in, const int* in_sizes, int n_in,
                              void* d_out, int out_size, void* d_ws, size_t ws_size,
                              hipStream_t stream) {
  const float* x      = (const float*)d_in[0];
  const int*   ei     = (const int*)d_in[1];
  const float* bias   = (const float*)d_in[3];
  const float* conv_w = (const float*)d_in[4];
  const float* conv_b = (const float*)d_in[5];
  const float* wq = (const float*)d_in[6];
  const float* bq = (const float*)d_in[7];
  const float* wk = (const float*)d_in[8];
  const float* bk = (const float*)d_in[9];
  const float* wv = (const float*)d_in[10];
  const float* bv = (const float*)d_in[11];
  const float* wo = (const float*)d_in[12];
  const float* bo = (const float*)d_in[13];
  const float* w1 = (const float*)d_in[14];
  const float* b1 = (const float*)d_in[15];
  const float* w2 = (const float*)d_in[16];
  const float* b2 = (const float*)d_in[17];
  const float* g1 = (const float*)d_in[18];
  const float* be1 = (const float*)d_in[19];
  const float* g2 = (const float*)d_in[20];
  const float* be2 = (const float*)d_in[21];
  const float* g3 = (const float*)d_in[22];
  const float* be3 = (const float*)d_in[23];
  int E = in_sizes[1] / 2;

  float* ws = (float*)d_ws;
  const size_t NC = (size_t)NN * CC;
  float* xw     = ws;            // conv xws
  float* h1pre  = ws + NC;
  float* qb     = ws + 2 * NC;   // fp16 Q (2MB used)
  float* kb     = ws + 3 * NC;   // fp16 K
  float* vb     = ws + 4 * NC;   // fp16 V
  float* h2pre  = ws + 5 * NC;   // wo-gemm out
  float* outbuf = ws + 6 * NC;   // attn f32 out; then combine out (MLP input)
  float* hid    = ws + 2 * NC;   // reuse qb+kb after attention
  float* h3pre  = ws + 4 * NC;   // reuse vb after attention consumed
  float* st     = ws + 7 * NC;   // 768 floats BN sums
  float* dinv   = ws + 7 * NC + 768;
  int*   degi     = (int*)(ws + 7 * NC + 768 + NN);
  int*   rowstart = degi + NN;
  int*   cursor   = rowstart + NN + 1;
  int*   col      = cursor + NN;

  hipMemsetAsync(degi, 0, NN * sizeof(int), stream);
  hipMemsetAsync(st, 0, 768 * sizeof(float), stream);

  // ---- GCN branch
  count_deg_int_k<<<(E + 255) / 256, 256, 0, stream>>>(ei + E, degi, E);
  scan_k<<<1, 256, 0, stream>>>(degi, rowstart, cursor, dinv);
  bucket_k<<<(E + 255) / 256, 256, 0, stream>>>(ei, ei + E, cursor, col, E);
  mgemm_k<128><<<dim3(NN / 16, 1), 256, 0, stream>>>(x, conv_w, nullptr, nullptr, dinv, xw, CC, 1.f, 0, 0);
  gather_k<<<NN / 2, 256, 0, stream>>>(rowstart, col, xw, dinv, conv_b, x, h1pre);
  bn_stats_k<<<NN / 64, 256, 0, stream>>>(h1pre, st + 0, st + 128);

  // ---- attention branch (Q/K/V as fp16; attn writes merged f32 directly)
  mgemm_k<128><<<dim3(NN / 16, 1), 256, 0, stream>>>(x, wq, bq, nullptr, nullptr, qb, CC, 0.25f, 0, 1);
  mgemm_k<128><<<dim3(NN / 16, 1), 256, 0, stream>>>(x, wk, bk, nullptr, nullptr, kb, CC, 1.f, 0, 1);
  mgemm_k<128><<<dim3(NN / 16, 1), 256, 0, stream>>>(x, wv, bv, nullptr, nullptr, vb, CC, 1.f, 0, 1);
  attn_k<<<512, 256, 0, stream>>>((const half_t*)qb, (const half_t*)kb, (const half_t*)vb, bias, outbuf);
  mgemm_k<128><<<dim3(NN / 16, 1), 256, 0, stream>>>(outbuf, wo, bo, x, nullptr, h2pre, CC, 1.f, 0, 0);
  bn_stats_k<<<NN / 64, 256, 0, stream>>>(h2pre, st + 256, st + 384);

  // ---- combine + MLP (BN finalizes fused)
  combine_k<<<NC / 256, 256, 0, stream>>>(h1pre, h2pre, st, g1, be1, g2, be2, outbuf);
  mgemm_k<128><<<dim3(NN / 16, 2), 256, 0, stream>>>(outbuf, w1, b1, nullptr, nullptr, hid, 2 * CC, 1.f, 1, 0);
  mgemm_k<256><<<dim3(NN / 16, 1), 256, 0, stream>>>(hid, w2, b2, outbuf, nullptr, h3pre, CC, 1.f, 0, 0);
  bn_stats_k<<<NN / 64, 256, 0, stream>>>(h3pre, st + 512, st + 640);
  bn_apply_k<<<NC / 256, 256, 0, stream>>>(h3pre, st, g3, be3, (float*)d_out);
}